// Round 2
// baseline (876.888 us; speedup 1.0000x reference)
//
#include <hip/hip_runtime.h>

// ---------------------------------------------------------------------------
// out[n] = sum_f ( z_nf^T W_f z_nf - log(clip(det(W_f S1_f + I),1e-5,1e5)) )
//          + log(n1/n2)
// N=4096, K=256, P2=96
//
// ws usage (kept minimal — 263,168 B total; round 1's 4.98 MB ws use is the
// prime suspect for post-timing corruption of the harness's pristine copies):
//   partial: 16*4096 f32 at offset 0        (262,144 B)
//   logdet : 256 f32     at offset 262144   (1,024 B)
//
// Key identity: z^T W z == z^T W^T z, so the MFMA B-operand can be loaded
// from natural W rows (contiguous k) — no transpose, no precomputed buffer.
// ---------------------------------------------------------------------------

typedef __attribute__((ext_vector_type(8))) short bf16x8;
typedef __attribute__((ext_vector_type(4))) float f32x4;

__device__ __forceinline__ unsigned short f2bf(float x) {
  unsigned int u = __builtin_bit_cast(unsigned int, x);
  u += 0x7fffu + ((u >> 16) & 1u);   // round-to-nearest-even
  return (unsigned short)(u >> 16);
}
__device__ __forceinline__ float bf2f(unsigned short h) {
  unsigned int u = ((unsigned int)h) << 16;
  return __builtin_bit_cast(float, u);
}

// ---------------------------------------------------------------------------
// Kernel 1: per-frequency  A = W @ S1 + I  (fp32, LDS-chunked GEMM),
// LU with partial pivoting (perm-array, no physical swaps) -> clipped logdet.
// |det| ~ 1e74 >> 1e5, so the clip collapses to +/-log(1e5) by det sign
// (matching the reference, whose fp32 det overflows to +/-inf).
// ---------------------------------------------------------------------------
__global__ __launch_bounds__(256) void det_kernel(
    const float* __restrict__ W, const float* __restrict__ S1,
    float* __restrict__ logdet) {
  __shared__ float Al[96 * 97];
  __shared__ float Wc[96 * 33];   // W[:, kc*32 .. +32)
  __shared__ float Sc[32 * 97];   // S1[kc*32 .. +32, :]
  __shared__ int perm[96];
  __shared__ int pivphys;
  __shared__ float pivval;
  __shared__ int swapsign;

  const int t = threadIdx.x;
  const int f = blockIdx.x;
  const float4* Wg4 = reinterpret_cast<const float4*>(W + (size_t)f * 9216);
  const float4* Sg4 = reinterpret_cast<const float4*>(S1 + (size_t)f * 9216);

  if (t < 96) perm[t] = t;
  if (t == 0) swapsign = 0;

  const int ty = t >> 4, tx = t & 15;
  const int i0 = ty * 6, j0 = tx * 6;
  float acc[6][6];
#pragma unroll
  for (int a = 0; a < 6; ++a)
#pragma unroll
    for (int b = 0; b < 6; ++b) acc[a][b] = 0.f;

  for (int kc = 0; kc < 3; ++kc) {
    // stage W chunk: Wc[i][kk] = W[i][kc*32+kk]   (3072 floats = 768 float4)
#pragma unroll
    for (int it = 0; it < 3; ++it) {
      int c = t + it * 256;
      int i = c >> 3;              // 8 float4 per 32-wide row
      int k4 = (c & 7) << 2;
      float4 v = Wg4[i * 24 + kc * 8 + (c & 7)];
      Wc[i * 33 + k4 + 0] = v.x;
      Wc[i * 33 + k4 + 1] = v.y;
      Wc[i * 33 + k4 + 2] = v.z;
      Wc[i * 33 + k4 + 3] = v.w;
    }
    // stage S1 chunk: Sc[kk][j] = S1[kc*32+kk][j]
#pragma unroll
    for (int it = 0; it < 3; ++it) {
      int c = t + it * 256;
      int kk = c / 24;
      int j4 = (c % 24) << 2;
      float4 v = Sg4[kc * 768 + c];
      Sc[kk * 97 + j4 + 0] = v.x;
      Sc[kk * 97 + j4 + 1] = v.y;
      Sc[kk * 97 + j4 + 2] = v.z;
      Sc[kk * 97 + j4 + 3] = v.w;
    }
    __syncthreads();
    // partial matmul
    for (int kk = 0; kk < 32; ++kk) {
      float wv[6], sv[6];
#pragma unroll
      for (int a = 0; a < 6; ++a) wv[a] = Wc[(i0 + a) * 33 + kk];
#pragma unroll
      for (int b = 0; b < 6; ++b) sv[b] = Sc[kk * 97 + j0 + b];
#pragma unroll
      for (int a = 0; a < 6; ++a)
#pragma unroll
        for (int b = 0; b < 6; ++b) acc[a][b] += wv[a] * sv[b];
    }
    __syncthreads();
  }
  // A = W@S1 + I into Al
#pragma unroll
  for (int a = 0; a < 6; ++a)
#pragma unroll
    for (int b = 0; b < 6; ++b) {
      int i = i0 + a, j = j0 + b;
      Al[i * 97 + j] = acc[a][b] + ((i == j) ? 1.f : 0.f);
    }
  __syncthreads();

  // LU with partial pivoting via permutation array
  for (int k = 0; k < 96; ++k) {
    if (t < 64) {
      float bv = -1.f;
      int bi = 0x7fffffff;
      for (int i = k + t; i < 96; i += 64) {
        float v = fabsf(Al[perm[i] * 97 + k]);
        if (v > bv) { bv = v; bi = i; }
      }
#pragma unroll
      for (int m = 1; m < 64; m <<= 1) {
        float ov = __shfl_xor(bv, m);
        int oi = __shfl_xor(bi, m);
        if (ov > bv || (ov == bv && oi < bi)) { bv = ov; bi = oi; }
      }
      if (t == 0) {
        if (bi != k) {
          int tmp = perm[k]; perm[k] = perm[bi]; perm[bi] = tmp;
          swapsign ^= 1;
        }
        pivphys = perm[k];
        pivval = Al[perm[k] * 97 + k];
      }
    }
    __syncthreads();
    const int pk = pivphys;
    const float pv = pivval;
    const int ty8 = t >> 5, tx32 = t & 31;
    for (int li = k + 1 + ty8; li < 96; li += 8) {
      int pr = perm[li];
      float L = Al[pr * 97 + k] / pv;
      for (int j = k + 1 + tx32; j < 96; j += 32) {
        Al[pr * 97 + j] -= L * Al[pk * 97 + j];
      }
    }
    __syncthreads();
  }

  if (t < 64) {
    float ls = 0.f;
    int neg = 0;
    for (int kk = t; kk < 96; kk += 64) {
      float v = Al[perm[kk] * 97 + kk];
      ls += logf(fabsf(v));
      if (v < 0.f) neg ^= 1;
    }
#pragma unroll
    for (int m = 1; m < 64; m <<= 1) {
      ls += __shfl_xor(ls, m);
      neg ^= __shfl_xor(neg, m);
    }
    if (t == 0) {
      const float LMIN = -11.5129254f, LMAX = 11.5129254f;  // log(1e-5),log(1e5)
      float c;
      if (neg ^ swapsign) c = LMIN;                 // det <= 0 -> clip to 1e-5
      else c = fminf(fmaxf(ls, LMIN), LMAX);
      logdet[f] = c;
    }
  }
}

// ---------------------------------------------------------------------------
// Kernel 2: quad[n,f] via bf16 MFMA.  Block = (128-row n-tile) x (16-freq
// f-tile), 256 threads = 4 waves.  Per freq: stage z-tile (fp32->bf16) and
// W rows (fp32->bf16, natural layout) into padded LDS, compute
// Y = Z @ W^T with 16x16x32 MFMA (quadratic form is transpose-invariant),
// row-dot Y with z (C layout), accumulate across 16 freqs, shfl-reduce,
// write per-(n, f-tile) partials to ws.
// LDS row stride 104 shorts (208 B): MFMA b128 reads land 2-way = free.
// ---------------------------------------------------------------------------
#define ZLD 104

__global__ __launch_bounds__(256) void quad_kernel(
    const float* __restrict__ z, const float* __restrict__ W,
    float* __restrict__ partial) {
  __shared__ alignas(16) unsigned short Zb[128 * ZLD];
  __shared__ alignas(16) unsigned short Wb[96 * ZLD];

  const int tid = threadIdx.x;
  const int lane = tid & 63, wave = tid >> 6;
  const int n0 = blockIdx.x * 128;
  const int f0 = blockIdx.y * 16;
  const int lrow = lane & 15;
  const int lq = lane >> 4;
  const int lk8 = lq * 8;
  const int rgrp = tid >> 3;   // 0..31 (row within 32-row pass)
  const int cgrp = tid & 7;    // 0..7  (16B chunk group)

  float dotacc[2][4];
#pragma unroll
  for (int mt = 0; mt < 2; ++mt)
#pragma unroll
    for (int i = 0; i < 4; ++i) dotacc[mt][i] = 0.f;

  for (int ff = 0; ff < 16; ++ff) {
    const int f = f0 + ff;
    // ---- stage z tile: 8 threads/row, 128B-contiguous wave segments ----
#pragma unroll
    for (int p = 0; p < 4; ++p) {
      int r = p * 32 + rgrp;
      const float4* src = reinterpret_cast<const float4*>(
          z + (size_t)(n0 + r) * 24576 + (size_t)f * 96);
#pragma unroll
      for (int cc = 0; cc < 3; ++cc) {
        int c = cgrp + cc * 8;           // 0..23
        float4 d = src[c];
        ushort4 s;
        s.x = f2bf(d.x); s.y = f2bf(d.y); s.z = f2bf(d.z); s.w = f2bf(d.w);
        *reinterpret_cast<ushort4*>(&Zb[r * ZLD + c * 4]) = s;
      }
    }
    // ---- stage W rows (natural layout): 2304 float4, 9 per thread ----
    const float4* wsrc =
        reinterpret_cast<const float4*>(W + (size_t)f * 9216);
#pragma unroll
    for (int it = 0; it < 9; ++it) {
      int c = tid + it * 256;            // 0..2303
      int k = c / 24, q4 = (c % 24) << 2;
      float4 d = wsrc[c];
      ushort4 s;
      s.x = f2bf(d.x); s.y = f2bf(d.y); s.z = f2bf(d.z); s.w = f2bf(d.w);
      *reinterpret_cast<ushort4*>(&Wb[k * ZLD + q4]) = s;
    }
    __syncthreads();

    // ---- MFMA: Y(128x96) = Z @ W^T; wave handles 32 rows ----
    // B-fragment lane c reads W row c over contiguous k -> B[k][c]=W[c][k],
    // so Y[m][c] = sum_k z[m][k] W[c][k]; epilogue dot over c gives z^T W z.
    f32x4 acc[2][6];
#pragma unroll
    for (int mt = 0; mt < 2; ++mt)
#pragma unroll
      for (int nt = 0; nt < 6; ++nt) acc[mt][nt] = (f32x4){0.f, 0.f, 0.f, 0.f};

#pragma unroll
    for (int ks = 0; ks < 3; ++ks) {
      bf16x8 a0 = *reinterpret_cast<const bf16x8*>(
          &Zb[(wave * 32 + lrow) * ZLD + ks * 32 + lk8]);
      bf16x8 a1 = *reinterpret_cast<const bf16x8*>(
          &Zb[(wave * 32 + 16 + lrow) * ZLD + ks * 32 + lk8]);
#pragma unroll
      for (int nt = 0; nt < 6; ++nt) {
        bf16x8 b = *reinterpret_cast<const bf16x8*>(
            &Wb[(nt * 16 + lrow) * ZLD + ks * 32 + lk8]);
        acc[0][nt] =
            __builtin_amdgcn_mfma_f32_16x16x32_bf16(a0, b, acc[0][nt], 0, 0, 0);
        acc[1][nt] =
            __builtin_amdgcn_mfma_f32_16x16x32_bf16(a1, b, acc[1][nt], 0, 0, 0);
      }
    }

    // ---- epilogue: row-dot in C layout (col=lane&15, row=(lane>>4)*4+reg) --
#pragma unroll
    for (int mt = 0; mt < 2; ++mt) {
      int rbase = wave * 32 + mt * 16 + lq * 4;
#pragma unroll
      for (int i = 0; i < 4; ++i) {
        int row = rbase + i;
        float s = 0.f;
#pragma unroll
        for (int nt = 0; nt < 6; ++nt) {
          float zv = bf2f(Zb[row * ZLD + nt * 16 + lrow]);
          s += acc[mt][nt][i] * zv;
        }
        dotacc[mt][i] += s;
      }
    }
    __syncthreads();   // LDS reused next freq
  }

  // reduce partial dots across the 16 lanes of each quad-group
#pragma unroll
  for (int mt = 0; mt < 2; ++mt)
#pragma unroll
    for (int i = 0; i < 4; ++i) {
      float v = dotacc[mt][i];
      v += __shfl_xor(v, 1);
      v += __shfl_xor(v, 2);
      v += __shfl_xor(v, 4);
      v += __shfl_xor(v, 8);
      dotacc[mt][i] = v;
    }
  if (lrow == 0) {
#pragma unroll
    for (int mt = 0; mt < 2; ++mt) {
      int row = wave * 32 + mt * 16 + lq * 4;
      float4 o = {dotacc[mt][0], dotacc[mt][1], dotacc[mt][2], dotacc[mt][3]};
      *reinterpret_cast<float4*>(
          &partial[(size_t)blockIdx.y * 4096 + n0 + row]) = o;
    }
  }
}

// ---------------------------------------------------------------------------
// Kernel 3: out[n] = sum_ft partial[ft][n] - sum_f logdet[f] + log(n1/n2)
// ---------------------------------------------------------------------------
__global__ __launch_bounds__(256) void finalize_kernel(
    const float* __restrict__ partial, const float* __restrict__ logdet,
    const int* __restrict__ n1p, const int* __restrict__ n2p,
    float* __restrict__ out) {
  __shared__ float red[256];
  const int t = threadIdx.x;
  red[t] = logdet[t];
  __syncthreads();
  for (int s = 128; s > 0; s >>= 1) {
    if (t < s) red[t] += red[t + s];
    __syncthreads();
  }
  const float S = red[0];
  const int n = blockIdx.x * 256 + t;
  float acc = 0.f;
#pragma unroll
  for (int ft = 0; ft < 16; ++ft) acc += partial[ft * 4096 + n];
  const float cst = logf((float)(*n1p) / (float)(*n2p));
  out[n] = acc - S + cst;
}

// ---------------------------------------------------------------------------
extern "C" void kernel_launch(void* const* d_in, const int* in_sizes, int n_in,
                              void* d_out, int out_size, void* d_ws,
                              size_t ws_size, hipStream_t stream) {
  const float* z  = (const float*)d_in[0];
  const float* s1 = (const float*)d_in[1];
  // d_in[2] = sigma_2 (unused by the reference)
  const float* w  = (const float*)d_in[3];
  const int* n1   = (const int*)d_in[4];
  const int* n2   = (const int*)d_in[5];
  float* out      = (float*)d_out;

  char* ws = (char*)d_ws;
  float* partial = (float*)ws;                 // 16*4096*4 = 262,144 B
  float* logdet  = (float*)(ws + 262144);      // 256*4     =   1,024 B

  det_kernel<<<dim3(256), dim3(256), 0, stream>>>(w, s1, logdet);
  quad_kernel<<<dim3(32, 16), dim3(256), 0, stream>>>(z, w, partial);
  finalize_kernel<<<dim3(16), dim3(256), 0, stream>>>(partial, logdet, n1, n2,
                                                      out);
}

// Round 3
// 874.352 us; speedup vs baseline: 1.0029x; 1.0029x over previous
//
#include <hip/hip_runtime.h>

// ---------------------------------------------------------------------------
// out[n] = sum_f ( z_nf^T W_f z_nf - log(clip(det(W_f S1_f + I),1e-5,1e5)) )
//          + log(n1/n2)
// N=4096, K=256, P2=96
//
// R3: det_kernel rewritten as one-wave-per-frequency (64 thr x 256 blocks):
//  - GEMM A = W@S1+I with 12x12 register tile/lane, K chunked by 32 via LDS
//  - LU w/ partial pivoting: physical row swaps, float4 row updates
//    (Al stride 100 dwords == 4 mod 32 -> uniform bank coverage for b128),
//    pivot-row reads are same-address broadcasts (free)
//  - single-wave barriers are ~free; no cross-wave serialization
// quad/finalize unchanged from R2 (passed, absmax 32).
// ---------------------------------------------------------------------------

typedef __attribute__((ext_vector_type(8))) short bf16x8;
typedef __attribute__((ext_vector_type(4))) float f32x4;

__device__ __forceinline__ unsigned short f2bf(float x) {
  unsigned int u = __builtin_bit_cast(unsigned int, x);
  u += 0x7fffu + ((u >> 16) & 1u);   // round-to-nearest-even
  return (unsigned short)(u >> 16);
}
__device__ __forceinline__ float bf2f(unsigned short h) {
  unsigned int u = ((unsigned int)h) << 16;
  return __builtin_bit_cast(float, u);
}

// ---------------------------------------------------------------------------
// Kernel 1: per-frequency logdet, one wave per frequency.
// ---------------------------------------------------------------------------
#define ALD 100   // Al row stride (dwords); 100 % 32 == 4 -> uniform b128 banks
#define WLD 35    // Wc row stride; 12*35 % 32 == 4 -> GEMM W-reads spread banks

__global__ __launch_bounds__(64) void det_kernel(
    const float* __restrict__ W, const float* __restrict__ S1,
    float* __restrict__ logdet) {
  __shared__ alignas(16) float Al[96 * ALD];   // 38,400 B
  __shared__ alignas(16) float Wc[96 * WLD];   // 13,440 B
  __shared__ alignas(16) float Sc[32 * 100];   // 12,800 B   (total 64,640 B)

  const int lane = threadIdx.x;
  const int f = blockIdx.x;
  const float* Wg = W + (size_t)f * 9216;
  const float* Sg = S1 + (size_t)f * 9216;

  const int i0 = (lane >> 3) * 12;   // lane tile: rows i0..i0+11
  const int j0 = (lane & 7) * 12;    //            cols j0..j0+11

  float acc[12][12];
#pragma unroll
  for (int a = 0; a < 12; ++a)
#pragma unroll
    for (int b = 0; b < 12; ++b) acc[a][b] = 0.f;

  for (int kc = 0; kc < 3; ++kc) {
    // stage Wc[i][kk] = W[i][kc*32+kk]  (768 float4 loads, b32 scatter)
#pragma unroll
    for (int it = 0; it < 12; ++it) {
      int c = lane + it * 64;          // 0..767
      int i = c >> 3;
      int k4 = (c & 7) << 2;
      const float4 v =
          *reinterpret_cast<const float4*>(Wg + i * 96 + kc * 32 + k4);
      Wc[i * WLD + k4 + 0] = v.x;
      Wc[i * WLD + k4 + 1] = v.y;
      Wc[i * WLD + k4 + 2] = v.z;
      Wc[i * WLD + k4 + 3] = v.w;
    }
    // stage Sc[kk][j] = S1[kc*32+kk][j]  (768 float4, b128 stores)
#pragma unroll
    for (int it = 0; it < 12; ++it) {
      int c = lane + it * 64;
      int kk = c / 24;
      int j4 = (c % 24) << 2;
      const float4 v =
          *reinterpret_cast<const float4*>(Sg + (kc * 32 + kk) * 96 + j4);
      *reinterpret_cast<float4*>(&Sc[kk * 100 + j4]) = v;
    }
    __syncthreads();
#pragma unroll 2
    for (int kk = 0; kk < 32; ++kk) {
      float wv[12];
#pragma unroll
      for (int r = 0; r < 12; ++r) wv[r] = Wc[(i0 + r) * WLD + kk];
      float sv[12];
      const float4 s0 = *reinterpret_cast<const float4*>(&Sc[kk * 100 + j0]);
      const float4 s1 =
          *reinterpret_cast<const float4*>(&Sc[kk * 100 + j0 + 4]);
      const float4 s2 =
          *reinterpret_cast<const float4*>(&Sc[kk * 100 + j0 + 8]);
      sv[0] = s0.x; sv[1] = s0.y; sv[2] = s0.z; sv[3] = s0.w;
      sv[4] = s1.x; sv[5] = s1.y; sv[6] = s1.z; sv[7] = s1.w;
      sv[8] = s2.x; sv[9] = s2.y; sv[10] = s2.z; sv[11] = s2.w;
#pragma unroll
      for (int a = 0; a < 12; ++a)
#pragma unroll
        for (int b = 0; b < 12; ++b) acc[a][b] += wv[a] * sv[b];
    }
    __syncthreads();
  }

  // Al = acc + I
#pragma unroll
  for (int a = 0; a < 12; ++a) {
    int i = i0 + a;
#pragma unroll
    for (int c4 = 0; c4 < 3; ++c4) {
      float4 v;
      v.x = acc[a][c4 * 4 + 0] + ((i == j0 + c4 * 4 + 0) ? 1.f : 0.f);
      v.y = acc[a][c4 * 4 + 1] + ((i == j0 + c4 * 4 + 1) ? 1.f : 0.f);
      v.z = acc[a][c4 * 4 + 2] + ((i == j0 + c4 * 4 + 2) ? 1.f : 0.f);
      v.w = acc[a][c4 * 4 + 3] + ((i == j0 + c4 * 4 + 3) ? 1.f : 0.f);
      *reinterpret_cast<float4*>(&Al[i * ALD + j0 + c4 * 4]) = v;
    }
  }
  __syncthreads();

  // ---- LU with partial pivoting, physical row swaps, single wave ----
  int sgn = 0;
  for (int k = 0; k < 96; ++k) {
    // pivot search over col k, rows k..95 (every lane ends with argmax)
    float bv = -1.f;
    int bi = k;
    for (int i = k + lane; i < 96; i += 64) {
      float v = fabsf(Al[i * ALD + k]);
      if (v > bv) { bv = v; bi = i; }
    }
#pragma unroll
    for (int m = 1; m < 64; m <<= 1) {
      float ov = __shfl_xor(bv, m);
      int oi = __shfl_xor(bi, m);
      if (ov > bv || (ov == bv && oi < bi)) { bv = ov; bi = oi; }
    }
    // physical swap rows k <-> bi (bi uniform across lanes)
    if (bi != k) {
      sgn ^= 1;
      if (lane < 24) {
        float4 a = *reinterpret_cast<float4*>(&Al[k * ALD + lane * 4]);
        float4 b = *reinterpret_cast<float4*>(&Al[bi * ALD + lane * 4]);
        *reinterpret_cast<float4*>(&Al[k * ALD + lane * 4]) = b;
        *reinterpret_cast<float4*>(&Al[bi * ALD + lane * 4]) = a;
      }
    }
    __syncthreads();   // single-wave barrier: cheap; orders swap vs update

    const float pv = Al[k * ALD + k];      // broadcast read
    const int j4s = (k + 1) >> 2;
    for (int li = k + 1 + lane; li < 96; li += 64) {
      const float L = Al[li * ALD + k] / pv;
      for (int j4 = j4s; j4 < 24; ++j4) {
        float4 a = *reinterpret_cast<float4*>(&Al[li * ALD + j4 * 4]);
        const float4 p =
            *reinterpret_cast<const float4*>(&Al[k * ALD + j4 * 4]);
        a.x -= L * p.x;
        a.y -= L * p.y;
        a.z -= L * p.z;
        a.w -= L * p.w;
        *reinterpret_cast<float4*>(&Al[li * ALD + j4 * 4]) = a;
      }
    }
    __syncthreads();
  }

  // logdet from U diagonal
  float ls = 0.f;
  int neg = 0;
  for (int kk = lane; kk < 96; kk += 64) {
    float v = Al[kk * ALD + kk];
    ls += logf(fabsf(v));
    if (v < 0.f) neg ^= 1;
  }
#pragma unroll
  for (int m = 1; m < 64; m <<= 1) {
    ls += __shfl_xor(ls, m);
    neg ^= __shfl_xor(neg, m);
  }
  if (lane == 0) {
    const float LMIN = -11.5129254f, LMAX = 11.5129254f;  // log(1e-5), log(1e5)
    float c;
    if (neg ^ sgn) c = LMIN;              // det <= 0 -> clipped to 1e-5
    else c = fminf(fmaxf(ls, LMIN), LMAX);
    logdet[f] = c;
  }
}

// ---------------------------------------------------------------------------
// Kernel 2: quad[n,f] via bf16 MFMA (unchanged from R2 — passed, ~110 us).
// ---------------------------------------------------------------------------
#define ZLD 104

__global__ __launch_bounds__(256) void quad_kernel(
    const float* __restrict__ z, const float* __restrict__ W,
    float* __restrict__ partial) {
  __shared__ alignas(16) unsigned short Zb[128 * ZLD];
  __shared__ alignas(16) unsigned short Wb[96 * ZLD];

  const int tid = threadIdx.x;
  const int lane = tid & 63, wave = tid >> 6;
  const int n0 = blockIdx.x * 128;
  const int f0 = blockIdx.y * 16;
  const int lrow = lane & 15;
  const int lq = lane >> 4;
  const int lk8 = lq * 8;
  const int rgrp = tid >> 3;   // 0..31
  const int cgrp = tid & 7;    // 0..7

  float dotacc[2][4];
#pragma unroll
  for (int mt = 0; mt < 2; ++mt)
#pragma unroll
    for (int i = 0; i < 4; ++i) dotacc[mt][i] = 0.f;

  for (int ff = 0; ff < 16; ++ff) {
    const int f = f0 + ff;
    // ---- stage z tile: 8 threads/row, contiguous wave segments ----
#pragma unroll
    for (int p = 0; p < 4; ++p) {
      int r = p * 32 + rgrp;
      const float4* src = reinterpret_cast<const float4*>(
          z + (size_t)(n0 + r) * 24576 + (size_t)f * 96);
#pragma unroll
      for (int cc = 0; cc < 3; ++cc) {
        int c = cgrp + cc * 8;           // 0..23
        float4 d = src[c];
        ushort4 s;
        s.x = f2bf(d.x); s.y = f2bf(d.y); s.z = f2bf(d.z); s.w = f2bf(d.w);
        *reinterpret_cast<ushort4*>(&Zb[r * ZLD + c * 4]) = s;
      }
    }
    // ---- stage W rows (natural layout): 2304 float4, 9 per thread ----
    const float4* wsrc =
        reinterpret_cast<const float4*>(W + (size_t)f * 9216);
#pragma unroll
    for (int it = 0; it < 9; ++it) {
      int c = tid + it * 256;            // 0..2303
      int k = c / 24, q4 = (c % 24) << 2;
      float4 d = wsrc[c];
      ushort4 s;
      s.x = f2bf(d.x); s.y = f2bf(d.y); s.z = f2bf(d.z); s.w = f2bf(d.w);
      *reinterpret_cast<ushort4*>(&Wb[k * ZLD + q4]) = s;
    }
    __syncthreads();

    // ---- MFMA: Y(128x96) = Z @ W^T; wave handles 32 rows ----
    f32x4 acc[2][6];
#pragma unroll
    for (int mt = 0; mt < 2; ++mt)
#pragma unroll
      for (int nt = 0; nt < 6; ++nt) acc[mt][nt] = (f32x4){0.f, 0.f, 0.f, 0.f};

#pragma unroll
    for (int ks = 0; ks < 3; ++ks) {
      bf16x8 a0 = *reinterpret_cast<const bf16x8*>(
          &Zb[(wave * 32 + lrow) * ZLD + ks * 32 + lk8]);
      bf16x8 a1 = *reinterpret_cast<const bf16x8*>(
          &Zb[(wave * 32 + 16 + lrow) * ZLD + ks * 32 + lk8]);
#pragma unroll
      for (int nt = 0; nt < 6; ++nt) {
        bf16x8 b = *reinterpret_cast<const bf16x8*>(
            &Wb[(nt * 16 + lrow) * ZLD + ks * 32 + lk8]);
        acc[0][nt] =
            __builtin_amdgcn_mfma_f32_16x16x32_bf16(a0, b, acc[0][nt], 0, 0, 0);
        acc[1][nt] =
            __builtin_amdgcn_mfma_f32_16x16x32_bf16(a1, b, acc[1][nt], 0, 0, 0);
      }
    }

    // ---- epilogue: row-dot in C layout (col=lane&15, row=(lane>>4)*4+reg) --
#pragma unroll
    for (int mt = 0; mt < 2; ++mt) {
      int rbase = wave * 32 + mt * 16 + lq * 4;
#pragma unroll
      for (int i = 0; i < 4; ++i) {
        int row = rbase + i;
        float s = 0.f;
#pragma unroll
        for (int nt = 0; nt < 6; ++nt) {
          float zv = bf2f(Zb[row * ZLD + nt * 16 + lrow]);
          s += acc[mt][nt][i] * zv;
        }
        dotacc[mt][i] += s;
      }
    }
    __syncthreads();
  }

#pragma unroll
  for (int mt = 0; mt < 2; ++mt)
#pragma unroll
    for (int i = 0; i < 4; ++i) {
      float v = dotacc[mt][i];
      v += __shfl_xor(v, 1);
      v += __shfl_xor(v, 2);
      v += __shfl_xor(v, 4);
      v += __shfl_xor(v, 8);
      dotacc[mt][i] = v;
    }
  if (lrow == 0) {
#pragma unroll
    for (int mt = 0; mt < 2; ++mt) {
      int row = wave * 32 + mt * 16 + lq * 4;
      float4 o = {dotacc[mt][0], dotacc[mt][1], dotacc[mt][2], dotacc[mt][3]};
      *reinterpret_cast<float4*>(
          &partial[(size_t)blockIdx.y * 4096 + n0 + row]) = o;
    }
  }
}

// ---------------------------------------------------------------------------
// Kernel 3: out[n] = sum_ft partial[ft][n] - sum_f logdet[f] + log(n1/n2)
// ---------------------------------------------------------------------------
__global__ __launch_bounds__(256) void finalize_kernel(
    const float* __restrict__ partial, const float* __restrict__ logdet,
    const int* __restrict__ n1p, const int* __restrict__ n2p,
    float* __restrict__ out) {
  __shared__ float red[256];
  const int t = threadIdx.x;
  red[t] = logdet[t];
  __syncthreads();
  for (int s = 128; s > 0; s >>= 1) {
    if (t < s) red[t] += red[t + s];
    __syncthreads();
  }
  const float S = red[0];
  const int n = blockIdx.x * 256 + t;
  float acc = 0.f;
#pragma unroll
  for (int ft = 0; ft < 16; ++ft) acc += partial[ft * 4096 + n];
  const float cst = logf((float)(*n1p) / (float)(*n2p));
  out[n] = acc - S + cst;
}

// ---------------------------------------------------------------------------
extern "C" void kernel_launch(void* const* d_in, const int* in_sizes, int n_in,
                              void* d_out, int out_size, void* d_ws,
                              size_t ws_size, hipStream_t stream) {
  const float* z  = (const float*)d_in[0];
  const float* s1 = (const float*)d_in[1];
  // d_in[2] = sigma_2 (unused by the reference)
  const float* w  = (const float*)d_in[3];
  const int* n1   = (const int*)d_in[4];
  const int* n2   = (const int*)d_in[5];
  float* out      = (float*)d_out;

  char* ws = (char*)d_ws;
  float* partial = (float*)ws;                 // 16*4096*4 = 262,144 B
  float* logdet  = (float*)(ws + 262144);      // 256*4     =   1,024 B

  det_kernel<<<dim3(256), dim3(64), 0, stream>>>(w, s1, logdet);
  quad_kernel<<<dim3(32, 16), dim3(256), 0, stream>>>(z, w, partial);
  finalize_kernel<<<dim3(16), dim3(256), 0, stream>>>(partial, logdet, n1, n2,
                                                      out);
}